// Round 1
// baseline (2853.414 us; speedup 1.0000x reference)
//
#include <hip/hip_runtime.h>

#define DD 256
#define NROWS (524288 * 2)
#define NTILES (NROWS / 16)          // 65536
#define NBLOCKS 256
#define WPB 8                        // waves per block
#define ITERS (NTILES / (NBLOCKS * WPB))  // 32

typedef __attribute__((ext_vector_type(8))) short short8;
typedef __attribute__((ext_vector_type(4))) float f32x4;

__device__ inline unsigned short f2bf(float x) {
    unsigned u = __builtin_bit_cast(unsigned, x);
    u += 0x7fffu + ((u >> 16) & 1u);   // round-to-nearest-even
    return (unsigned short)(u >> 16);
}

// ---------------- W = Wo @ Wv (bf16), c = Wo @ bv + bo ----------------
__global__ void wprep_kernel(const float* __restrict__ in_w,
                             const float* __restrict__ in_b,
                             const float* __restrict__ out_w,
                             const float* __restrict__ out_b,
                             unsigned short* __restrict__ Wbf,
                             float* __restrict__ cvec) {
    __shared__ float worow[DD];
    __shared__ float part[DD];
    const int i = blockIdx.x;   // output row of W
    const int j = threadIdx.x;  // output col of W
    worow[j] = out_w[i * DD + j];
    __syncthreads();
    const float* wv = in_w + 512 * DD;  // Wv = rows 512..767 of in_proj_w
    float s = 0.f;
    for (int k = 0; k < DD; ++k) s = fmaf(worow[k], wv[k * DD + j], s);
    Wbf[i * DD + j] = f2bf(s);
    part[j] = worow[j] * in_b[512 + j];  // bv[j]
    __syncthreads();
    if (j == 0) {
        float c = out_b[i];
        for (int k = 0; k < DD; ++k) c += part[k];
        cvec[i] = c;
    }
}

// ---------------- main fused kernel ----------------
// y[r] = x[r] + x[r^1] @ W^T + c ; out[r] = LN(y[r]) * gamma + beta
// per wave: 16-row tile. MFMA orientation: A = W tile (M=out-col), B = x rows (N=batch row).
__global__ __launch_bounds__(512, 2) void fused_kernel(
    const float* __restrict__ x, const unsigned short* __restrict__ Wbf,
    const float* __restrict__ cvec, const float* __restrict__ gamma,
    const float* __restrict__ beta, float* __restrict__ out) {
    extern __shared__ char lds_raw[];
    unsigned short* Wl = (unsigned short*)lds_raw;  // 256x256 bf16, swizzled (128 KiB)
    float* cl = (float*)(lds_raw + 131072);
    float* gl = cl + 256;
    float* bl = gl + 256;

    const int tid = threadIdx.x;

    // Stage W into LDS with XOR swizzle on 16B chunks: byte = n*512 + ((kc*16) ^ ((n&7)<<4))
    for (int r = 0; r < 16; ++r) {
        int chunk = r * 512 + tid;      // 8192 chunks of 8 bf16
        int n = chunk >> 5;             // W row
        int kc = chunk & 31;            // 16B chunk in row
        f32x4 v = *(const f32x4*)(Wbf + n * 256 + kc * 8);
        int off = n * 512 + ((kc * 16) ^ ((n & 7) << 4));
        *(f32x4*)((char*)Wl + off) = v;
    }
    if (tid < 256) {
        cl[tid] = cvec[tid];
        gl[tid] = gamma[tid];
        bl[tid] = beta[tid];
    }
    __syncthreads();

    const int wave = tid >> 6;
    const int lane = tid & 63;
    const int m = lane & 15;   // batch row within tile (B-operand col / C col)
    const int g = lane >> 4;   // k-group / C row group

    for (int it = 0; it < ITERS; ++it) {
        const int tile = blockIdx.x * (WPB * ITERS) + it * WPB + wave;
        const long r0 = (long)tile * 16;
        const float* xb = x + (r0 + (m ^ 1)) * DD;  // partner row -> B operand
        const float* xr = x + (r0 + m) * DD;        // own row -> residual

        // B operand loads: 8 k-steps x 32B per lane (the one required x read)
        f32x4 bx[8][2];
#pragma unroll
        for (int s = 0; s < 8; ++s) {
            bx[s][0] = *(const f32x4*)(xb + s * 32 + g * 8);
            bx[s][1] = *(const f32x4*)(xb + s * 32 + g * 8 + 4);
        }

        f32x4 acc[16];
#pragma unroll
        for (int nt = 0; nt < 16; ++nt) acc[nt] = f32x4{0.f, 0.f, 0.f, 0.f};

#pragma unroll
        for (int s = 0; s < 8; ++s) {
            short8 bfrag;
#pragma unroll
            for (int j = 0; j < 4; ++j) {
                bfrag[j]     = (short)f2bf(bx[s][0][j]);
                bfrag[j + 4] = (short)f2bf(bx[s][1][j]);
            }
#pragma unroll
            for (int nt = 0; nt < 16; ++nt) {
                int n = nt * 16 + m;  // W row = output col (A-operand row)
                int off = n * 512 + ((s * 64 + g * 16) ^ ((n & 7) << 4));
                short8 afrag = *(const short8*)((const char*)Wl + off);
                acc[nt] = __builtin_amdgcn_mfma_f32_16x16x32_bf16(afrag, bfrag, acc[nt], 0, 0, 0);
            }
        }

        // residual loads (likely L2 hits: same lines as partner-loads of this tile)
        f32x4 rx[16];
#pragma unroll
        for (int nt = 0; nt < 16; ++nt)
            rx[nt] = *(const f32x4*)(xr + nt * 16 + g * 4);

        // epilogue: y = acc + x + c ; LN over the row (4 lanes share a row)
        float s1 = 0.f, s2 = 0.f;
#pragma unroll
        for (int nt = 0; nt < 16; ++nt) {
            f32x4 cc = *(const f32x4*)(cl + nt * 16 + g * 4);
            f32x4 y = acc[nt] + rx[nt] + cc;
            acc[nt] = y;
#pragma unroll
            for (int i2 = 0; i2 < 4; ++i2) {
                s1 += y[i2];
                s2 = fmaf(y[i2], y[i2], s2);
            }
        }
        s1 += __shfl_xor(s1, 16); s2 += __shfl_xor(s2, 16);
        s1 += __shfl_xor(s1, 32); s2 += __shfl_xor(s2, 32);
        const float mu = s1 * (1.f / 256.f);
        const float var = s2 * (1.f / 256.f) - mu * mu;
        const float rs = rsqrtf(var + 1e-5f);

        float* op = out + (r0 + m) * DD;
#pragma unroll
        for (int nt = 0; nt < 16; ++nt) {
            f32x4 gg = *(const f32x4*)(gl + nt * 16 + g * 4);
            f32x4 bb = *(const f32x4*)(bl + nt * 16 + g * 4);
            f32x4 y = acc[nt];
            f32x4 o;
#pragma unroll
            for (int i2 = 0; i2 < 4; ++i2)
                o[i2] = fmaf((y[i2] - mu) * rs, gg[i2], bb[i2]);
            *(f32x4*)(op + nt * 16 + g * 4) = o;
        }
    }
}

extern "C" void kernel_launch(void* const* d_in, const int* in_sizes, int n_in,
                              void* d_out, int out_size, void* d_ws, size_t ws_size,
                              hipStream_t stream) {
    const float* x     = (const float*)d_in[0];
    const float* in_w  = (const float*)d_in[1];
    const float* in_b  = (const float*)d_in[2];
    const float* out_w = (const float*)d_in[3];
    const float* out_b = (const float*)d_in[4];
    const float* gamma = (const float*)d_in[5];
    const float* beta  = (const float*)d_in[6];
    float* out = (float*)d_out;

    unsigned short* Wbf = (unsigned short*)d_ws;           // 128 KiB bf16 W
    float* cvec = (float*)((char*)d_ws + 131072);          // 1 KiB c

    hipLaunchKernelGGL(wprep_kernel, dim3(256), dim3(256), 0, stream,
                       in_w, in_b, out_w, out_b, Wbf, cvec);

    const int lds_bytes = 131072 + 3 * 256 * 4;  // W + c + gamma + beta
    hipFuncSetAttribute(reinterpret_cast<const void*>(fused_kernel),
                        hipFuncAttributeMaxDynamicSharedMemorySize, lds_bytes);
    hipLaunchKernelGGL(fused_kernel, dim3(NBLOCKS), dim3(512), lds_bytes, stream,
                       x, Wbf, cvec, gamma, beta, out);
}

// Round 2
// 442.873 us; speedup vs baseline: 6.4430x; 6.4430x over previous
//
#include <hip/hip_runtime.h>

#define DD 256
#define TOTROWS (524288 * 2)
#define NBLOCKS 256
#define RPI 64                               // rows per iteration per block
#define ITERS (TOTROWS / (NBLOCKS * RPI))    // 64
#define XROW 528                             // bf16 row stride (bytes) = 33*16 (pad vs 512)
#define YROW 1040                            // fp32 row stride (bytes) = 65*16 (pad vs 1024)
#define XB0 0
#define XB1 (RPI * XROW)                     // 33792
#define YB (2 * RPI * XROW)                  // 67584
#define SUMS (YB + RPI * YROW)               // 134144
#define MURS (SUMS + RPI * 8 * 8)            // 138240
#define LDS_TOTAL (MURS + RPI * 8)           // 138752

typedef __attribute__((ext_vector_type(8))) short short8;
typedef __attribute__((ext_vector_type(4))) float f32x4;
typedef __attribute__((ext_vector_type(2))) float f32x2;
typedef __attribute__((ext_vector_type(4))) unsigned short u16x4;

__device__ inline unsigned short f2bf(float x) {
    unsigned u = __builtin_bit_cast(unsigned, x);
    u += 0x7fffu + ((u >> 16) & 1u);  // RNE
    return (unsigned short)(u >> 16);
}
__device__ inline float bf2f(unsigned short h) {
    unsigned u = ((unsigned)h) << 16;
    return __builtin_bit_cast(float, u);
}

// ---------------- W = Wo @ Wv (bf16), c = Wo @ bv + bo ----------------
__global__ void wprep_kernel(const float* __restrict__ in_w,
                             const float* __restrict__ in_b,
                             const float* __restrict__ out_w,
                             const float* __restrict__ out_b,
                             unsigned short* __restrict__ Wbf,
                             float* __restrict__ cvec) {
    __shared__ float worow[DD];
    __shared__ float part[DD];
    const int i = blockIdx.x;   // output row of W
    const int j = threadIdx.x;  // output col of W
    worow[j] = out_w[i * DD + j];
    __syncthreads();
    const float* wv = in_w + 512 * DD;  // Wv = rows 512..767 of in_proj_w
    float s = 0.f;
    for (int k = 0; k < DD; ++k) s = fmaf(worow[k], wv[k * DD + j], s);
    Wbf[i * DD + j] = f2bf(s);
    part[j] = worow[j] * in_b[512 + j];  // bv[j]
    __syncthreads();
    if (j == 0) {
        float c = out_b[i];
        for (int k = 0; k < DD; ++k) c += part[k];
        cvec[i] = c;
    }
}

// ---------------- main fused kernel ----------------
// Per block: W split across 8 waves (32 out-cols each, A-frags in registers).
// Per iter: stage 64 rows of x (fp32->bf16) into LDS coalesced; every wave
// computes its 32 cols for all 64 rows via MFMA; LN reduced across waves in
// LDS; y normalized into LDS fp32 buffer; coalesced store.
__global__ __launch_bounds__(512, 2) void fused_kernel(
    const float* __restrict__ x, const unsigned short* __restrict__ Wbf,
    const float* __restrict__ cvec, const float* __restrict__ gamma,
    const float* __restrict__ beta, float* __restrict__ out) {
    extern __shared__ __align__(16) char lds[];
    const int tid = threadIdx.x;
    const int w = tid >> 6, lane = tid & 63;
    const int m = lane & 15, g = lane >> 4;

    // A fragments: af[n2][s] = W[w*32+n2*16+m][k = s*32+g*8 .. +8]
    short8 af[2][8];
#pragma unroll
    for (int n2 = 0; n2 < 2; ++n2)
#pragma unroll
        for (int s = 0; s < 8; ++s)
            af[n2][s] = *(const short8*)(Wbf + (w * 32 + n2 * 16 + m) * 256 + s * 32 + g * 8);

    f32x4 creg[2], greg[2], breg[2];
#pragma unroll
    for (int n2 = 0; n2 < 2; ++n2) {
        const int c0 = w * 32 + n2 * 16 + g * 4;
        creg[n2] = *(const f32x4*)(cvec + c0);
        greg[n2] = *(const f32x4*)(gamma + c0);
        breg[n2] = *(const f32x4*)(beta + c0);
    }

    const size_t rowbase = (size_t)blockIdx.x * (ITERS * RPI);

    f32x4 sv[8];
    // prologue: stage iter 0 into buffer 0
#pragma unroll
    for (int j = 0; j < 8; ++j)
        sv[j] = *(const f32x4*)(x + rowbase * DD + j * 2048 + tid * 4);
#pragma unroll
    for (int j = 0; j < 8; ++j) {
        const int row = j * 8 + w;  // one full row per wave per j
        u16x4 h = {f2bf(sv[j][0]), f2bf(sv[j][1]), f2bf(sv[j][2]), f2bf(sv[j][3])};
        *(u16x4*)(lds + XB0 + row * XROW + lane * 8) = h;
    }
    __syncthreads();

    for (int it = 0; it < ITERS; ++it) {
        const int xb = (it & 1) ? XB1 : XB0;
        const int xn = (it & 1) ? XB0 : XB1;
        const size_t r0 = rowbase + (size_t)it * RPI;

        // T14: issue next tile's global loads now, consume after compute
        if (it + 1 < ITERS) {
#pragma unroll
            for (int j = 0; j < 8; ++j)
                sv[j] = *(const f32x4*)(x + (r0 + RPI) * DD + j * 2048 + tid * 4);
        }

        // MFMA phase: B = partner rows from LDS (bf16, no cvt in hot loop)
        f32x4 acc[4][2];
#pragma unroll
        for (int t = 0; t < 4; ++t) {
            acc[t][0] = f32x4{0.f, 0.f, 0.f, 0.f};
            acc[t][1] = f32x4{0.f, 0.f, 0.f, 0.f};
        }
#pragma unroll
        for (int t = 0; t < 4; ++t) {
            const int rowp = t * 16 + (m ^ 1);  // partner row
            const char* bbase = lds + xb + rowp * XROW + g * 16;
            short8 bf_[8];
#pragma unroll
            for (int s = 0; s < 8; ++s) bf_[s] = *(const short8*)(bbase + s * 64);
#pragma unroll
            for (int s = 0; s < 8; ++s) {
                acc[t][0] = __builtin_amdgcn_mfma_f32_16x16x32_bf16(af[0][s], bf_[s], acc[t][0], 0, 0, 0);
                acc[t][1] = __builtin_amdgcn_mfma_f32_16x16x32_bf16(af[1][s], bf_[s], acc[t][1], 0, 0, 0);
            }
        }

        // residual (bf16 from LDS) + bias, partial LN sums -> LDS
#pragma unroll
        for (int t = 0; t < 4; ++t) {
            const int rowm = t * 16 + m;
            float s1 = 0.f, s2 = 0.f;
#pragma unroll
            for (int n2 = 0; n2 < 2; ++n2) {
                u16x4 rh = *(const u16x4*)(lds + xb + rowm * XROW + w * 64 + n2 * 32 + g * 8);
                f32x4 y = acc[t][n2];
#pragma unroll
                for (int i = 0; i < 4; ++i) y[i] += bf2f(rh[i]) + creg[n2][i];
                acc[t][n2] = y;
#pragma unroll
                for (int i = 0; i < 4; ++i) {
                    s1 += y[i];
                    s2 = fmaf(y[i], y[i], s2);
                }
            }
            s1 += __shfl_xor(s1, 16); s2 += __shfl_xor(s2, 16);
            s1 += __shfl_xor(s1, 32); s2 += __shfl_xor(s2, 32);
            if (g == 0) *(f32x2*)(lds + SUMS + (rowm * 8 + w) * 8) = f32x2{s1, s2};
        }
        __syncthreads();

        // cross-wave LN reduce: 512 threads = 64 rows x 8 partials
        {
            const int r = tid >> 3, w2 = tid & 7;
            f32x2 p = *(const f32x2*)(lds + SUMS + (r * 8 + w2) * 8);
            float a = p[0], b = p[1];
            a += __shfl_xor(a, 1); b += __shfl_xor(b, 1);
            a += __shfl_xor(a, 2); b += __shfl_xor(b, 2);
            a += __shfl_xor(a, 4); b += __shfl_xor(b, 4);
            if (w2 == 0) {
                const float mu = a * (1.f / 256.f);
                const float var = b * (1.f / 256.f) - mu * mu;
                *(f32x2*)(lds + MURS + r * 8) = f32x2{mu, rsqrtf(var + 1e-5f)};
            }
        }
        __syncthreads();

        // normalize -> ybuf (LDS fp32)
#pragma unroll
        for (int t = 0; t < 4; ++t) {
            const int rowm = t * 16 + m;
            f32x2 mr = *(const f32x2*)(lds + MURS + rowm * 8);
#pragma unroll
            for (int n2 = 0; n2 < 2; ++n2) {
                f32x4 y = acc[t][n2], o;
#pragma unroll
                for (int i = 0; i < 4; ++i)
                    o[i] = fmaf((y[i] - mr[0]) * mr[1], greg[n2][i], breg[n2][i]);
                *(f32x4*)(lds + YB + rowm * YROW + w * 128 + n2 * 64 + g * 16) = o;
            }
        }

        // consume prefetch: cvt + write bf16 tile for next iter
        if (it + 1 < ITERS) {
#pragma unroll
            for (int j = 0; j < 8; ++j) {
                const int row = j * 8 + w;
                u16x4 h = {f2bf(sv[j][0]), f2bf(sv[j][1]), f2bf(sv[j][2]), f2bf(sv[j][3])};
                *(u16x4*)(lds + xn + row * XROW + lane * 8) = h;
            }
        }
        __syncthreads();

        // coalesced store: each wave writes full contiguous rows
#pragma unroll
        for (int j = 0; j < 8; ++j) {
            const int row = j * 8 + w;
            f32x4 v = *(const f32x4*)(lds + YB + row * YROW + lane * 16);
            *(f32x4*)(out + (r0 + row) * DD + lane * 4) = v;
        }
    }
}

extern "C" void kernel_launch(void* const* d_in, const int* in_sizes, int n_in,
                              void* d_out, int out_size, void* d_ws, size_t ws_size,
                              hipStream_t stream) {
    const float* x     = (const float*)d_in[0];
    const float* in_w  = (const float*)d_in[1];
    const float* in_b  = (const float*)d_in[2];
    const float* out_w = (const float*)d_in[3];
    const float* out_b = (const float*)d_in[4];
    const float* gamma = (const float*)d_in[5];
    const float* beta  = (const float*)d_in[6];
    float* out = (float*)d_out;

    unsigned short* Wbf = (unsigned short*)d_ws;   // 128 KiB bf16 W = Wo@Wv
    float* cvec = (float*)((char*)d_ws + 131072);  // 1 KiB c = Wo@bv + bo

    hipLaunchKernelGGL(wprep_kernel, dim3(256), dim3(256), 0, stream,
                       in_w, in_b, out_w, out_b, Wbf, cvec);

    hipFuncSetAttribute(reinterpret_cast<const void*>(fused_kernel),
                        hipFuncAttributeMaxDynamicSharedMemorySize, LDS_TOTAL);
    hipLaunchKernelGGL(fused_kernel, dim3(NBLOCKS), dim3(512), LDS_TOTAL, stream,
                       x, Wbf, cvec, gamma, beta, out);
}